// Round 2
// baseline (234.906 us; speedup 1.0000x reference)
//
#include <hip/hip_runtime.h>
#include <hip/hip_bf16.h>

typedef __bf16 bf16_t;
typedef bf16_t bf16x8 __attribute__((ext_vector_type(8)));
typedef bf16_t bf16x4 __attribute__((ext_vector_type(4)));
typedef float  f32x4  __attribute__((ext_vector_type(4)));

#define S_LEN  2048
#define D_HEAD 64
#define KT     64     // keys per tile
#define QB     128    // q rows per block

// Layout facts used (HW-verified per guide):
//  - mfma_f32_16x16x32_bf16 C/D: col = lane&15, row = (lane>>4)*4 + reg  [m89/m91]
//  - A operand: row = lane&15, k-chunk indexed by lane>>4 (exact k-permutation
//    irrelevant: both A and B use the same mapping -> dot invariant)
//  - B operand: col = lane&15, same k-chunking.

__global__ __launch_bounds__(256, 2)
void sdpa_fwd(const float* __restrict__ Qg, const float* __restrict__ Kg,
              const float* __restrict__ Vg, float* __restrict__ Og)
{
    __shared__ bf16_t kbuf[KT * D_HEAD];        // K row-major [key][d], swizzled
    __shared__ bf16_t vbuf[D_HEAD * KT];        // V^T [d][key], swizzled
    __shared__ bf16_t pbuf[8 * 16 * KT];        // per (wave,qs): P^T as [q][key], swizzled

    const int n  = blockIdx.x;
    const int o  = ((n & 7) << 7) | (n >> 3);   // XCD-chunked swizzle (1024 % 8 == 0)
    const int bh = o >> 4;
    const int qi = o & 15;
    const int q0 = qi * QB;

    const int t   = threadIdx.x;
    const int w   = t >> 6;
    const int l   = t & 63;
    const int l15 = l & 15;
    const int lg  = l >> 4;

    const size_t hoff = (size_t)bh * S_LEN * D_HEAD;
    const float* Qh = Qg + hoff;
    const float* Kh = Kg + hoff;
    const float* Vh = Vg + hoff;
    float*       Oh = Og + hoff;

    // ---- Q fragments (B operand: col = q, k = d) ----
    bf16x8 qf[2][2];
#pragma unroll
    for (int qs = 0; qs < 2; ++qs) {
        const int qrow = q0 + w * 32 + qs * 16 + l15;
        const float* qp = Qh + (size_t)qrow * D_HEAD + lg * 8;
#pragma unroll
        for (int dh = 0; dh < 2; ++dh) {
            f32x4 a = *(const f32x4*)(qp + dh * 32);
            f32x4 b = *(const f32x4*)(qp + dh * 32 + 4);
            bf16x8 f;
            f[0] = (bf16_t)a[0]; f[1] = (bf16_t)a[1];
            f[2] = (bf16_t)a[2]; f[3] = (bf16_t)a[3];
            f[4] = (bf16_t)b[0]; f[5] = (bf16_t)b[1];
            f[6] = (bf16_t)b[2]; f[7] = (bf16_t)b[3];
            qf[qs][dh] = f;
        }
    }

    f32x4 acc[2][4];
#pragma unroll
    for (int qs = 0; qs < 2; ++qs)
#pragma unroll
        for (int ng = 0; ng < 4; ++ng) {
            f32x4 z = {0.0f, 0.0f, 0.0f, 0.0f};
            acc[qs][ng] = z;
        }

    float m_run[2] = { -1e30f, -1e30f };
    float l_run[2] = { 0.0f, 0.0f };

    bf16_t* pw = pbuf + (size_t)(w * 2) * (16 * KT);

    const int nkt = 2 * qi + 2;  // tiles covering keys [0, q0+127]
    for (int kt = 0; kt < nkt; ++kt) {
        __syncthreads();   // previous tile's compute done before LDS overwrite
        // ---- stage K tile (row-major bf16, XOR swizzle on 16B slot) ----
        {
            const int rr = t >> 3;
            const int cc = (t & 7) * 8;
#pragma unroll
            for (int p = 0; p < 2; ++p) {
                const int key = rr + p * 32;
                const float* kp = Kh + (size_t)(kt * KT + key) * D_HEAD + cc;
                f32x4 a = *(const f32x4*)kp;
                f32x4 b = *(const f32x4*)(kp + 4);
                bf16x8 f;
                f[0] = (bf16_t)a[0]; f[1] = (bf16_t)a[1];
                f[2] = (bf16_t)a[2]; f[3] = (bf16_t)a[3];
                f[4] = (bf16_t)b[0]; f[5] = (bf16_t)b[1];
                f[6] = (bf16_t)b[2]; f[7] = (bf16_t)b[3];
                const int byte = (key * 128 + cc * 2) ^ ((key & 7) << 4);
                *(bf16x8*)((char*)kbuf + byte) = f;
            }
            // ---- stage V^T (d-major) : strided global reads, scalar swizzled writes ----
#pragma unroll
            for (int p = 0; p < 2; ++p) {
                const int key = (t >> 3) + p * 32;
                const float* vp = Vh + (size_t)(kt * KT + key) * D_HEAD + (t & 7);
#pragma unroll
                for (int j = 0; j < 8; ++j) {
                    const int d = (t & 7) + 8 * j;
                    const float x = vp[8 * j];
                    const int byte = (d * 128 + key * 2) ^ ((d & 7) << 4);
                    *(bf16_t*)((char*)vbuf + byte) = (bf16_t)x;
                }
            }
        }
        __syncthreads();

        if (kt * KT > q0 + w * 32 + 31) continue;  // tile fully masked for this wave

        // ---- K fragments (A operand of T = K·Q^T) ----
        bf16x8 kf_[4][2];
#pragma unroll
        for (int kg = 0; kg < 4; ++kg) {
            const int key  = kg * 16 + l15;
            const int rowb = key * 128;
            const int swz  = (key & 7) << 4;
#pragma unroll
            for (int dh = 0; dh < 2; ++dh) {
                const int byte = (rowb + dh * 64 + lg * 16) ^ swz;
                kf_[kg][dh] = *(const bf16x8*)((const char*)kbuf + byte);
            }
        }
        // ---- V^T fragments (A operand of O^T = V^T·P^T) ----
        bf16x8 vf_[4][2];
#pragma unroll
        for (int ng = 0; ng < 4; ++ng) {
            const int d    = ng * 16 + l15;
            const int rowb = d * 128;
            const int swz  = (d & 7) << 4;
#pragma unroll
            for (int kfi = 0; kfi < 2; ++kfi) {
                const int byte = (rowb + kfi * 64 + lg * 16) ^ swz;
                vf_[ng][kfi] = *(const bf16x8*)((const char*)vbuf + byte);
            }
        }

#pragma unroll
        for (int qs = 0; qs < 2; ++qs) {
            const int qsbase = q0 + w * 32 + qs * 16;
            if (kt * KT > qsbase + 15) continue;   // subtile fully masked
            const int qrow = qsbase + l15;

            // T = K·Q^T : T[key][q], lane holds q = l15, keys kg*16 + lg*4 + r
            f32x4 tf[4];
#pragma unroll
            for (int kg = 0; kg < 4; ++kg) {
                f32x4 c = {0.0f, 0.0f, 0.0f, 0.0f};
                c = __builtin_amdgcn_mfma_f32_16x16x32_bf16(kf_[kg][0], qf[qs][0], c, 0, 0, 0);
                c = __builtin_amdgcn_mfma_f32_16x16x32_bf16(kf_[kg][1], qf[qs][1], c, 0, 0, 0);
                tf[kg] = c;
            }

            // Mask needed unless the tile's LAST key <= the subtile's FIRST q row.
            // (Previous round compared against qsbase+15 -> last 16-row subtile of
            //  each diagonal block attended to future keys. absmax 0.866.)
            const bool need_mask = (kt * KT + KT - 1) > qsbase;
            float mx = -1e30f;
#pragma unroll
            for (int kg = 0; kg < 4; ++kg) {
#pragma unroll
                for (int r = 0; r < 4; ++r) {
                    float sv = tf[kg][r] * 0.125f;   // 1/sqrt(64)
                    if (need_mask) {
                        const int key = kt * KT + kg * 16 + lg * 4 + r;
                        if (key > qrow) sv = -10000.0f;  // matches reference masked_fill
                    }
                    tf[kg][r] = sv;
                    mx = fmaxf(mx, sv);
                }
            }
            mx = fmaxf(mx, __shfl_xor(mx, 16));
            mx = fmaxf(mx, __shfl_xor(mx, 32));
            const float mnew  = fmaxf(m_run[qs], mx);
            const float alpha = __expf(m_run[qs] - mnew);
            m_run[qs] = mnew;

            float sum = 0.0f;
#pragma unroll
            for (int kg = 0; kg < 4; ++kg) {
#pragma unroll
                for (int r = 0; r < 4; ++r) {
                    const float p = __expf(tf[kg][r] - mnew);
                    tf[kg][r] = p;
                    sum += p;
                }
            }
            sum += __shfl_xor(sum, 16);
            sum += __shfl_xor(sum, 32);
            l_run[qs] = l_run[qs] * alpha + sum;
#pragma unroll
            for (int ng = 0; ng < 4; ++ng)
                acc[qs][ng] *= alpha;

            // write P^T (bf16) into per-wave LDS: pbuf[q][key], swizzled
            bf16_t* pq = pw + qs * (16 * KT);
            const int prow = l15 * 128;
            const int pswz = (l15 & 7) << 4;
#pragma unroll
            for (int kg = 0; kg < 4; ++kg) {
                bf16x4 t4;
                t4[0] = (bf16_t)tf[kg][0];
                t4[1] = (bf16_t)tf[kg][1];
                t4[2] = (bf16_t)tf[kg][2];
                t4[3] = (bf16_t)tf[kg][3];
                const int byte = (prow + kg * 32 + lg * 8) ^ pswz;
                *(bf16x4*)((char*)pq + byte) = t4;
            }
            // cross-lane LDS dependency within the wave: drain DS queue
            asm volatile("s_waitcnt lgkmcnt(0)" ::: "memory");
            __builtin_amdgcn_sched_barrier(0);

#pragma unroll
            for (int kfi = 0; kfi < 2; ++kfi) {
                const int byte = (prow + kfi * 64 + lg * 16) ^ pswz;
                const bf16x8 pf = *(const bf16x8*)((const char*)pq + byte);
#pragma unroll
                for (int ng = 0; ng < 4; ++ng)
                    acc[qs][ng] = __builtin_amdgcn_mfma_f32_16x16x32_bf16(vf_[ng][kfi], pf, acc[qs][ng], 0, 0, 0);
            }
        }
    }

    // ---- epilogue: O = O^T normalized, stored back untransposed ----
#pragma unroll
    for (int qs = 0; qs < 2; ++qs) {
        const float inv  = 1.0f / l_run[qs];
        const int   qrow = q0 + w * 32 + qs * 16 + l15;
        float* op = Oh + (size_t)qrow * D_HEAD + lg * 4;
#pragma unroll
        for (int ng = 0; ng < 4; ++ng) {
            f32x4 v = acc[qs][ng];
            v *= inv;
            *(f32x4*)(op + ng * 16) = v;
        }
    }
}

extern "C" void kernel_launch(void* const* d_in, const int* in_sizes, int n_in,
                              void* d_out, int out_size, void* d_ws, size_t ws_size,
                              hipStream_t stream) {
    (void)in_sizes; (void)n_in; (void)d_ws; (void)ws_size; (void)out_size;
    const float* q = (const float*)d_in[0];
    const float* k = (const float*)d_in[1];
    const float* v = (const float*)d_in[2];
    // d_in[3] is the tril mask; causality applied analytically (identical).
    float* out = (float*)d_out;
    dim3 grid(1024), block(256);
    hipLaunchKernelGGL(sdpa_fwd, grid, block, 0, stream, q, k, v, out);
}

// Round 3
// 84.743 us; speedup vs baseline: 2.7720x; 2.7720x over previous
//
#include <hip/hip_runtime.h>
#include <hip/hip_bf16.h>

typedef __bf16 bf16_t;
typedef bf16_t bf16x8 __attribute__((ext_vector_type(8)));
typedef bf16_t bf16x4 __attribute__((ext_vector_type(4)));
typedef float  f32x4  __attribute__((ext_vector_type(4)));

#define KT 64     // keys per tile
#define DH 64     // head dim

// R3: balanced stripe-pairing (p, 15-p) -> uniform 34 tiles/block; 512 blocks
// x 512 threads (8 waves, 16 q-rows each); conflict-free vbuf swizzle;
// async-stage (T14) prefetch of next K/V tile; 1/8 scale folded into Q (exact).
//
// MFMA layout facts (HW-verified, guide m89/m91):
//   C/D: col = lane&15, row = (lane>>4)*4 + reg
//   A: row = lane&15; B: col = lane&15; k-slot = (lane>>4)*8 + j (same map for
//   A and B -> any common k-permutation is legal).

__global__ __launch_bounds__(512, 4)
void sdpa_fwd(const float* __restrict__ Qg, const float* __restrict__ Kg,
              const float* __restrict__ Vg, float* __restrict__ Og)
{
    __shared__ bf16_t kbuf[KT * DH];       // [key][d] slot-swz: slot = dc ^ (key&7)
    __shared__ bf16_t vbuf[DH * KT];       // [d][key] slot-swz: slot = kc ^ (d&7) ^ ((d>>3)&7)
    __shared__ bf16_t pbuf[8 * 16 * KT];   // per-wave 2KB: [q][key] slot-swz: slot = kc ^ (q&7)

    const int n  = blockIdx.x;
    const int o  = ((n & 7) << 6) | (n >> 3);   // XCD-chunked swizzle (512 % 8 == 0)
    const int bh = o >> 3;                      // 0..63  (b*16 + h)
    const int pr = o & 7;                       // stripe pair 0..7

    const int t   = threadIdx.x;
    const int w   = t >> 6;
    const int l15 = t & 15;
    const int lg  = (t >> 4) & 3;

    const size_t hoff = (size_t)bh * 2048 * DH;
    const float* Qh = Qg + hoff;
    const float* Kh = Kg + hoff;
    const float* Vh = Vg + hoff;
    float*       Oh = Og + hoff;

    // staging assignment: thread -> (key, d-chunk of 8)
    const int skey = t >> 3;        // 0..63
    const int sdc  = t & 7;         // d = sdc*8 + j

    f32x4 pk0, pk1, pv0, pv1;       // prefetch regs (T14)

    const int stripes[2] = { 15 - pr, pr };          // heavy stripe first
    const int ntile[2]   = { 2*(15-pr) + 2, 2*pr + 2 };  // sums to 34

    { // prologue: prefetch key-tile 0
        const float* kp = Kh + (size_t)skey * DH + sdc * 8;
        pk0 = *(const f32x4*)kp;  pk1 = *(const f32x4*)(kp + 4);
        const float* vp = Vh + (size_t)skey * DH + sdc * 8;
        pv0 = *(const f32x4*)vp;  pv1 = *(const f32x4*)(vp + 4);
    }

    for (int s = 0; s < 2; ++s) {
        const int qS   = stripes[s] * 128;
        const int nkt  = ntile[s];
        const int qsb  = qS + w * 16;      // this wave's 16-row subtile base
        const int qrow = qsb + l15;

        // ---- Q fragments, pre-scaled by 1/8 (exact in bf16) ----
        bf16x8 qf[2];
        {
            const float* qp = Qh + (size_t)qrow * DH + lg * 8;
#pragma unroll
            for (int dh2 = 0; dh2 < 2; ++dh2) {
                f32x4 a = *(const f32x4*)(qp + dh2 * 32);
                f32x4 b = *(const f32x4*)(qp + dh2 * 32 + 4);
                bf16x8 f;
                f[0] = (bf16_t)(a[0]*0.125f); f[1] = (bf16_t)(a[1]*0.125f);
                f[2] = (bf16_t)(a[2]*0.125f); f[3] = (bf16_t)(a[3]*0.125f);
                f[4] = (bf16_t)(b[0]*0.125f); f[5] = (bf16_t)(b[1]*0.125f);
                f[6] = (bf16_t)(b[2]*0.125f); f[7] = (bf16_t)(b[3]*0.125f);
                qf[dh2] = f;
            }
        }

        f32x4 acc[4];
#pragma unroll
        for (int ng = 0; ng < 4; ++ng) { f32x4 z = {0.f,0.f,0.f,0.f}; acc[ng] = z; }
        float m_run = -1e30f, l_run = 0.0f;

        for (int kt = 0; kt < nkt; ++kt) {
            __syncthreads();        // previous tile's compute done
            // ---- stage prefetched tile into LDS ----
            {
                bf16x8 f;
                f[0] = (bf16_t)pk0[0]; f[1] = (bf16_t)pk0[1];
                f[2] = (bf16_t)pk0[2]; f[3] = (bf16_t)pk0[3];
                f[4] = (bf16_t)pk1[0]; f[5] = (bf16_t)pk1[1];
                f[6] = (bf16_t)pk1[2]; f[7] = (bf16_t)pk1[3];
                *(bf16x8*)((char*)kbuf + skey*128 + ((sdc ^ (skey & 7)) << 4)) = f;
                float vv[8] = { pv0[0],pv0[1],pv0[2],pv0[3], pv1[0],pv1[1],pv1[2],pv1[3] };
#pragma unroll
                for (int j = 0; j < 8; ++j) {   // transpose scatter, ~2-way (free)
                    const int byte = (sdc*8 + j)*128
                                   + ((((skey >> 3) ^ j ^ sdc) & 7) << 4)
                                   + (skey & 7) * 2;
                    *(bf16_t*)((char*)vbuf + byte) = (bf16_t)vv[j];
                }
            }
            // ---- T14: issue next tile's global loads (in flight under compute) ----
            const bool last = (s == 1) && (kt == nkt - 1);
            if (!last) {
                const int nk = (kt + 1 < nkt) ? kt + 1 : 0;   // next stripe restarts at key 0
                const float* kp = Kh + (size_t)(nk*KT + skey) * DH + sdc * 8;
                pk0 = *(const f32x4*)kp;  pk1 = *(const f32x4*)(kp + 4);
                const float* vp = Vh + (size_t)(nk*KT + skey) * DH + sdc * 8;
                pv0 = *(const f32x4*)vp;  pv1 = *(const f32x4*)(vp + 4);
            }
            __syncthreads();        // tile ready

            if (kt * KT > qsb + 15) continue;   // fully masked for this wave

            // ---- T = K·Q^T : lane holds q = l15, keys kg*16 + lg*4 + r ----
            f32x4 tf[4];
#pragma unroll
            for (int kg = 0; kg < 4; ++kg) {
                f32x4 c = {0.f,0.f,0.f,0.f};
#pragma unroll
                for (int dh2 = 0; dh2 < 2; ++dh2) {
                    const int byte = (kg*16 + l15)*128 + (((dh2*4 + lg) ^ (l15 & 7)) << 4);
                    const bf16x8 kf = *(const bf16x8*)((const char*)kbuf + byte);
                    c = __builtin_amdgcn_mfma_f32_16x16x32_bf16(kf, qf[dh2], c, 0, 0, 0);
                }
                tf[kg] = c;
            }

            // mask unless tile's last key <= subtile's first row
            const bool need_mask = (kt*KT + KT - 1) > qsb;
            float mx = -1e30f;
#pragma unroll
            for (int kg = 0; kg < 4; ++kg) {
#pragma unroll
                for (int r = 0; r < 4; ++r) {
                    float sv = tf[kg][r];      // already scaled via Q
                    if (need_mask) {
                        const int key = kt*KT + kg*16 + lg*4 + r;
                        if (key > qrow) sv = -10000.0f;   // matches reference
                    }
                    tf[kg][r] = sv;
                    mx = fmaxf(mx, sv);
                }
            }
            mx = fmaxf(mx, __shfl_xor(mx, 16));
            mx = fmaxf(mx, __shfl_xor(mx, 32));
            const float mnew  = fmaxf(m_run, mx);
            const float alpha = __expf(m_run - mnew);
            m_run = mnew;

            float sum = 0.0f;
#pragma unroll
            for (int kg = 0; kg < 4; ++kg) {
#pragma unroll
                for (int r = 0; r < 4; ++r) {
                    const float p = __expf(tf[kg][r] - mnew);
                    tf[kg][r] = p;
                    sum += p;
                }
            }
            sum += __shfl_xor(sum, 16);
            sum += __shfl_xor(sum, 32);
            l_run = l_run * alpha + sum;
#pragma unroll
            for (int ng = 0; ng < 4; ++ng) acc[ng] *= alpha;

            // ---- P^T round-trip through per-wave LDS ----
            bf16_t* pq = pbuf + w * (16 * KT);
            const int prow = l15 * 128;
            const int pswz = l15 & 7;
#pragma unroll
            for (int kg = 0; kg < 4; ++kg) {
                bf16x4 t4;
                t4[0] = (bf16_t)tf[kg][0]; t4[1] = (bf16_t)tf[kg][1];
                t4[2] = (bf16_t)tf[kg][2]; t4[3] = (bf16_t)tf[kg][3];
                const int byte = prow + (((kg*2 + (lg >> 1)) ^ pswz) << 4) + (lg & 1)*8;
                *(bf16x4*)((char*)pq + byte) = t4;
            }
            asm volatile("s_waitcnt lgkmcnt(0)" ::: "memory");   // wave-internal LDS RAW
            __builtin_amdgcn_sched_barrier(0);                    // rule #18

            // ---- O^T += V^T·P^T ----
#pragma unroll
            for (int kfi = 0; kfi < 2; ++kfi) {
                const int pbyte = prow + (((kfi*4 + lg) ^ pswz) << 4);
                const bf16x8 pf = *(const bf16x8*)((const char*)pq + pbyte);
#pragma unroll
                for (int ng = 0; ng < 4; ++ng) {
                    const int vbyte = (ng*16 + l15)*128
                        + ((((kfi*4 + lg) ^ (l15 & 7) ^ ((ng*2 + (l15 >> 3)) & 7)) ) << 4);
                    const bf16x8 vf = *(const bf16x8*)((const char*)vbuf + vbyte);
                    acc[ng] = __builtin_amdgcn_mfma_f32_16x16x32_bf16(vf, pf, acc[ng], 0, 0, 0);
                }
            }
        }

        // ---- epilogue for this stripe: O row = acc^T / l ----
        const float inv = 1.0f / l_run;
        float* op = Oh + (size_t)qrow * DH + lg * 4;
#pragma unroll
        for (int ng = 0; ng < 4; ++ng) {
            f32x4 v = acc[ng];
            v *= inv;
            *(f32x4*)(op + ng * 16) = v;
        }
    }
}

extern "C" void kernel_launch(void* const* d_in, const int* in_sizes, int n_in,
                              void* d_out, int out_size, void* d_ws, size_t ws_size,
                              hipStream_t stream) {
    (void)in_sizes; (void)n_in; (void)d_ws; (void)ws_size; (void)out_size;
    const float* q = (const float*)d_in[0];
    const float* k = (const float*)d_in[1];
    const float* v = (const float*)d_in[2];
    // d_in[3] (tril mask) applied analytically — identical semantics.
    float* out = (float*)d_out;
    hipLaunchKernelGGL(sdpa_fwd, dim3(512), dim3(512), 0, stream, q, k, v, out);
}